// Round 7
// baseline (133.743 us; speedup 1.0000x reference)
//
#include <hip/hip_runtime.h>
#include <stdint.h>

#define D  1024
#define NK 4096
#define KA 1024   // A = z_hi fp16 (hi-only; rescue covers the error)
#define KB 1024   // B = cb_hi fp16
#define TAU 0.15f // flag margin: 21 sigma of hi*hi approx error
#define CW  0.12f // candidate window in rescue: ~17 sigma
#define MAXC 1024

// ---- 256x256 MFMA GEMM, fat-wave (128x128/wave) + counted-vmcnt pipeline ----
#define BK2 32
#define NT2 (KA / BK2)   // 32 k-tiles
#define NBUF 4           // 4 single-tile LDS buffers -> prefetch distance 2 (128 KB)

typedef __attribute__((ext_vector_type(8))) _Float16 f16x8;
typedef __attribute__((ext_vector_type(4))) float f32x4;
typedef unsigned long long u64;

__device__ __forceinline__ uint32_t fkey(float f) {
    uint32_t b = __float_as_uint(f);
    return (b & 0x80000000u) ? ~b : (b | 0x80000000u);
}
__device__ __forceinline__ float unfkey(uint32_t u) {
    uint32_t b = (u & 0x80000000u) ? (u & 0x7fffffffu) : ~u;
    return __uint_as_float(b);
}
__device__ __forceinline__ u64 umin64(u64 a, u64 b) { return a < b ? a : b; }
__device__ __forceinline__ u64 umax64(u64 a, u64 b) { return a > b ? a : b; }

__device__ __forceinline__ void gload16(void* lds, const void* g) {
    __builtin_amdgcn_global_load_lds(
        (const __attribute__((address_space(1))) unsigned int*)g,
        (__attribute__((address_space(3))) unsigned int*)lds, 16, 0, 0);
}

#define BAR()     __builtin_amdgcn_s_barrier()
#define VMCNT8()  asm volatile("s_waitcnt vmcnt(8)" ::: "memory")
#define VMCNT0()  asm volatile("s_waitcnt vmcnt(0)" ::: "memory")

// ---------------- cbnorm (fallback path only) ----------------
__global__ void cbnorm_kernel(const float* __restrict__ cb, float* __restrict__ cbn) {
    __shared__ float red[256];
    const int kk = threadIdx.x & 63;
    const int dc = threadIdx.x >> 6;
    const int k  = blockIdx.x * 64 + kk;
    float s = 0.f;
    for (int d = dc; d < D; d += 4) {
        float v = cb[d * NK + k];
        s = fmaf(v, v, s);
    }
    red[threadIdx.x] = s;
    __syncthreads();
    if (dc == 0) cbn[k] = (red[kk] + red[64 + kk]) + (red[128 + kk] + red[192 + kk]);
}

// ---------------- transpose + fp16 cast; cb branch also emits sumsq partials ----------------
// Also zeroes the rescue counter (block (0,0,0) thread 0) -> removes the memset dispatch.
__global__ __launch_bounds__(256) void split_transpose(
        const float* __restrict__ z, const float* __restrict__ cb,
        _Float16* __restrict__ Ap, _Float16* __restrict__ Bp,
        float* __restrict__ partial, int* __restrict__ ctr) {
    __shared__ float T[64][65];
    if (blockIdx.x == 0 && blockIdx.y == 0 && blockIdx.z == 0 && threadIdx.x == 0)
        *ctr = 0;
    const int isZ = (blockIdx.z == 0);
    const float* src = isZ ? z : cb;
    _Float16* dst = isZ ? Ap : Bp;
    const int n0 = blockIdx.x * 64, d0 = blockIdx.y * 64;
    const int t = threadIdx.x;
#pragma unroll
    for (int i = 0; i < 4; ++i) {
        int dl = (t >> 4) + i * 16;
        int nl = (t & 15) * 4;
        float4 v = *(const float4*)&src[(size_t)(d0 + dl) * NK + n0 + nl];
        T[dl][nl] = v.x; T[dl][nl + 1] = v.y; T[dl][nl + 2] = v.z; T[dl][nl + 3] = v.w;
    }
    __syncthreads();
    const int nr = t >> 2, dch = (t & 3) * 16;
    f16x8 h0, h1;
    float s = 0.f;
#pragma unroll
    for (int j = 0; j < 8; ++j) {
        float v = T[dch + j][nr];
        s = fmaf(v, v, s);
        h0[j] = (_Float16)v;
    }
#pragma unroll
    for (int j = 0; j < 8; ++j) {
        float v = T[dch + 8 + j][nr];
        s = fmaf(v, v, s);
        h1[j] = (_Float16)v;
    }
    size_t base = (size_t)(n0 + nr) * KA + d0 + dch;
    *(f16x8*)&dst[base]     = h0;
    *(f16x8*)&dst[base + 8] = h1;
    if (!isZ) {
        s += __shfl_xor(s, 1);
        s += __shfl_xor(s, 2);
        if ((t & 3) == 0) partial[(size_t)(d0 >> 6) * NK + n0 + nr] = s;
    }
}

// ---------------- 256x256 fp16 MFMA GEMM, fat-wave edition ----------------
// 4 waves (2M x 2N), wave output 128x128, acc[8][8] (256 VGPR, AITER-style
// fat-wave / 1 wave/SIMD). Rationale: with wave tile 128x64, LDS read traffic
// (96 KB/tile/CU) ~= MFMA work and the per-wave read->wait->MFMA order
// serializes the DS and matrix pipes (R1-R4 all plateau at 44-47us).
// 128x128 waves cut read amplification 3x -> 2x (64 KB/tile/CU ~1000 cyc
// < MFMA 1242 cyc) and give the wave 64 MFMAs per 24 memory ops -- the
// compiler's fine-grained lgkm interleave hides the DS pipe under the MFMA
// shadow within the wave. Counted-vmcnt distance-2 prefetch kept verbatim
// (8 stagings/thread/tile -> vmcnt(8)). cbn summed inline from partials.
__global__ __launch_bounds__(256, 1) void gemm_mfma(
        const _Float16* __restrict__ Ap, const _Float16* __restrict__ Bp,
        const float* __restrict__ partial, ulonglong2* __restrict__ tp) {
    __shared__ _Float16 As[NBUF][256 * BK2];   // 4 x 16 KB
    __shared__ _Float16 Bs[NBUF][256 * BK2];   // 4 x 16 KB
    const int tid = threadIdx.x;
    // XCD chunking: 8 XCDs x 32 wgs; chunk = 4 n-tiles x 8 k-tiles (bijective for 256 wgs)
    const int xcd = blockIdx.x & 7, idx = blockIdx.x >> 3;
    const int n0 = ((xcd >> 1) * 4 + (idx >> 3)) * 256;
    const int k0 = ((xcd & 1) * 8 + (idx & 7)) * 256;
    const int w = tid >> 6, l = tid & 63;
    const int wr = w >> 1, wc = w & 1;
    const int fr = l & 15, fq = l >> 4;

    f32x4 acc[8][8] = {};

    // staging: thread -> row tid>>2, 4 rounds of 64 rows per operand, source-swizzled
    const int srow = tid >> 2;
    const int swz = ((tid & 3) ^ ((tid >> 3) & 3)) * 8;
    const _Float16* gA = Ap + (size_t)(n0 + srow) * KA + swz;
    const _Float16* gB = Bp + (size_t)(k0 + srow) * KB + swz;
    const int rcol = (fq ^ ((fr >> 1) & 3)) * 8;   // swizzled read column (0-conflict, proven)

    // prologue: stage tiles 0 and 1; wait tile 0 (tile 1's 8 stay in flight)
#pragma unroll
    for (int i = 0; i < 4; ++i) gload16(&As[0][tid * 8 + i * 2048], gA + (size_t)(64 * i) * KA);
#pragma unroll
    for (int i = 0; i < 4; ++i) gload16(&Bs[0][tid * 8 + i * 2048], gB + (size_t)(64 * i) * KB);
#pragma unroll
    for (int i = 0; i < 4; ++i) gload16(&As[1][tid * 8 + i * 2048], gA + (size_t)(64 * i) * KA + BK2);
#pragma unroll
    for (int i = 0; i < 4; ++i) gload16(&Bs[1][tid * 8 + i * 2048], gB + (size_t)(64 * i) * KB + BK2);
    VMCNT8();
    BAR();

    for (int t = 0; t < NT2; ++t) {
        const int b = t & 3;
        const int pb = (t + 2) & 3;
        const _Float16* Ab = As[b];
        const _Float16* Bb = Bs[b];
        const bool st = (t + 2) < NT2;
        const size_t kofs = (size_t)(t + 2) * BK2;

        // B fragments (8 ni, held across the whole tile)
        f16x8 bb[8];
#pragma unroll
        for (int ni = 0; ni < 8; ++ni)
            bb[ni] = *(const f16x8*)&Bb[(wc * 128 + ni * 16 + fr) * BK2 + rcol];

        // stage tile t+2 (8 loads; land under the next tiles' MFMAs)
        if (st) {
#pragma unroll
            for (int i = 0; i < 4; ++i)
                gload16(&As[pb][tid * 8 + i * 2048], gA + (size_t)(64 * i) * KA + kofs);
#pragma unroll
            for (int i = 0; i < 4; ++i)
                gload16(&Bs[pb][tid * 8 + i * 2048], gB + (size_t)(64 * i) * KB + kofs);
        }

        // 64-MFMA cluster, A streamed one fragment at a time
        __builtin_amdgcn_s_setprio(1);
#pragma unroll
        for (int mi = 0; mi < 8; ++mi) {
            f16x8 a = *(const f16x8*)&Ab[(wr * 128 + mi * 16 + fr) * BK2 + rcol];
#pragma unroll
            for (int ni = 0; ni < 8; ++ni)
                acc[mi][ni] = __builtin_amdgcn_mfma_f32_16x16x32_f16(a, bb[ni], acc[mi][ni], 0, 0, 0);
        }
        __builtin_amdgcn_s_setprio(0);

        // tile boundary: counted wait + single rendezvous
        if (t < NT2 - 2) {
            VMCNT8();
        } else if (t == NT2 - 2) {
            VMCNT0();
        }
        if (t < NT2 - 1) BAR();
    }

    // ---- epilogue: inline cbn + float-domain best2, two 64-k groups per wave.
    // Exact ties imply gap < TAU -> flagged -> rescue recomputes in fp32 with
    // u64 smallest-k tie-breaking, so reference argmin semantics are preserved.
#pragma unroll
    for (int nh = 0; nh < 2; ++nh) {
        float cbv[4];
#pragma unroll
        for (int ni = 0; ni < 4; ++ni) {
            const int k = k0 + wc * 128 + nh * 64 + ni * 16 + fr;
            float s = 0.f;
#pragma unroll
            for (int j = 0; j < 16; ++j) s += partial[(size_t)j * NK + k];
            cbv[ni] = s;
        }
        const int kt64 = (k0 >> 6) + wc * 2 + nh;
#pragma unroll
        for (int mi = 0; mi < 8; ++mi) {
#pragma unroll
            for (int reg = 0; reg < 4; ++reg) {
                float b1f = 1e30f, b2f = 1e30f;
                int b1k = 0;
#pragma unroll
                for (int ni = 0; ni < 4; ++ni) {
                    float s = fmaf(-2.f, acc[mi][nh * 4 + ni][reg], cbv[ni]);
                    b2f = fminf(fmaxf(s, b1f), b2f);   // med3: new 2nd-best
                    if (s < b1f) { b1f = s; b1k = k0 + wc * 128 + nh * 64 + ni * 16 + fr; }
                }
#pragma unroll
                for (int m = 8; m >= 1; m >>= 1) {
                    float q1 = __shfl_xor(b1f, m);
                    int   qk = __shfl_xor(b1k, m);
                    float q2 = __shfl_xor(b2f, m);
                    b2f = fminf(fminf(b2f, q2), fmaxf(b1f, q1));
                    if (q1 < b1f) { b1f = q1; b1k = qk; }
                }
                if (fr == 0) {
                    int n = n0 + wr * 128 + mi * 16 + fq * 4 + reg;
                    ulonglong2 v;
                    v.x = ((u64)fkey(b1f) << 32) | (unsigned)b1k;
                    v.y = ((u64)fkey(b2f) << 32) | 0xffffffffu;
                    tp[(size_t)kt64 * NK + n] = v;
                }
            }
        }
    }
}

// ---------------- reduce 64 groups/token (4 stripes + LDS merge); flag near-ties ----------------
__global__ __launch_bounds__(256) void reduce_rows(
        const ulonglong2* __restrict__ tp, int* __restrict__ idx,
        int* __restrict__ rescue, int* __restrict__ ctr) {
    __shared__ ulonglong2 sh[4][64];
    const int no = threadIdx.x & 63, st = threadIdx.x >> 6;
    const int n = blockIdx.x * 64 + no;
    u64 b1 = ~0ull, b2 = ~0ull;
#pragma unroll 4
    for (int g = st * 16; g < st * 16 + 16; ++g) {
        ulonglong2 e = tp[(size_t)g * NK + n];
        u64 nb1 = umin64(b1, e.x);
        u64 nb2 = umin64(umax64(b1, e.x), umin64(b2, e.y));
        b1 = nb1; b2 = nb2;
    }
    ulonglong2 v; v.x = b1; v.y = b2;
    sh[st][no] = v;
    __syncthreads();
    if (st == 0) {
#pragma unroll
        for (int j = 1; j < 4; ++j) {
            ulonglong2 e = sh[j][no];
            u64 nb1 = umin64(b1, e.x);
            u64 nb2 = umin64(umax64(b1, e.x), umin64(b2, e.y));
            b1 = nb1; b2 = nb2;
        }
        idx[n] = (int)(b1 & 0xffffffffull);
        float f1 = unfkey((uint32_t)(b1 >> 32));
        float f2 = unfkey((uint32_t)(b2 >> 32));
        if (f2 - f1 < TAU) {
            int p = atomicAdd(ctr, 1);
            rescue[p] = n;
        }
    }
}

// ---------------- candidate-pruned exact fp32 rescore; writes idx directly ----------------
__global__ __launch_bounds__(256) void rescue_kernel(
        const float* __restrict__ z, const float* __restrict__ cb,
        const ulonglong2* __restrict__ tp, const int* __restrict__ rescue,
        const int* __restrict__ ctr, int* __restrict__ idx) {
    const int cnt = min(*ctr, NK);
    const int tid = threadIdx.x;
    const int lane = tid & 63, wv = tid >> 6;

    __shared__ float zn[D];
    __shared__ int cand[MAXC];
    __shared__ int ccnt, overflow;
    __shared__ u64 wred[4];

    for (int slot = blockIdx.x; slot < cnt; slot += gridDim.x) {
        const int n = rescue[slot];
        if (tid == 0) { ccnt = 0; overflow = 0; }
        for (int d = tid; d < D; d += 256) zn[d] = z[(size_t)d * NK + n];

        if (tid < 64) {   // wave 0: build candidate list
            ulonglong2 e = tp[(size_t)tid * NK + n];
            u64 m = e.x;
#pragma unroll
            for (int msk = 32; msk >= 1; msk >>= 1) m = umin64(m, __shfl_xor(m, msk));
            const float thr = unfkey((uint32_t)(m >> 32)) + CW;
            if (unfkey((uint32_t)(e.y >> 32)) < thr) {
                int p = atomicAdd(&ccnt, 64);
                if (p + 64 <= MAXC) {
                    for (int j = 0; j < 64; ++j) cand[p + j] = tid * 64 + j;
                } else overflow = 1;
            } else if (unfkey((uint32_t)(e.x >> 32)) < thr) {
                int p = atomicAdd(&ccnt, 1);
                if (p < MAXC) cand[p] = (int)(e.x & 0xffffffffull);
                else overflow = 1;
            }
        }
        __syncthreads();

        const int ovf = overflow;
        const int m = ovf ? NK : min(ccnt, MAXC);
        u64 best = ~0ull;
        for (int ci = wv; ci < m; ci += 4) {
            const int k = ovf ? ci : cand[ci];
            float s = 0.f, s2 = 0.f;
#pragma unroll
            for (int j = 0; j < 16; ++j) {
                float c = cb[(size_t)(lane + j * 64) * NK + k];
                s  = fmaf(zn[lane + j * 64], c, s);
                s2 = fmaf(c, c, s2);
            }
#pragma unroll
            for (int msk = 32; msk >= 1; msk >>= 1) {
                s  += __shfl_xor(s, msk);
                s2 += __shfl_xor(s2, msk);
            }
            float sc = s2 - 2.f * s;
            best = umin64(best, ((u64)fkey(sc) << 32) | (unsigned)k);
        }
        if (lane == 0) wred[wv] = best;
        __syncthreads();
        if (tid == 0)
            idx[n] = (int)(umin64(umin64(wred[0], wred[1]),
                                  umin64(wred[2], wred[3])) & 0xffffffffull);
        __syncthreads();   // protect zn/cand/ccnt reuse on the next strided slot
    }
}

// ---------------- fallback fp32 VALU GEMM (round-1, for small ws) ----------------
__global__ __launch_bounds__(256) void gemm_argmin(
        const float* __restrict__ z, const float* __restrict__ cb,
        const float* __restrict__ cbn, unsigned long long* __restrict__ best) {
    __shared__ float Zs[8][128];
    __shared__ float Cs[8][128];
    const int n0 = blockIdx.y * 128, k0 = blockIdx.x * 128;
    const int tid = threadIdx.x;
    const int tx = tid & 15, ty = tid >> 4;
    const int lr = tid >> 5, lc = (tid & 31) << 2;
    float acc[8][8];
#pragma unroll
    for (int i = 0; i < 8; ++i)
#pragma unroll
        for (int j = 0; j < 8; ++j) acc[i][j] = 0.f;
    for (int d0 = 0; d0 < D; d0 += 8) {
        float4 zv = *(const float4*)&z [(d0 + lr) * NK + n0 + lc];
        float4 cv = *(const float4*)&cb[(d0 + lr) * NK + k0 + lc];
        __syncthreads();
        *(float4*)&Zs[lr][lc] = zv;
        *(float4*)&Cs[lr][lc] = cv;
        __syncthreads();
#pragma unroll
        for (int dd = 0; dd < 8; ++dd) {
            float4 a0 = *(const float4*)&Zs[dd][ty * 8];
            float4 a1 = *(const float4*)&Zs[dd][ty * 8 + 4];
            float4 b0 = *(const float4*)&Cs[dd][tx * 8];
            float4 b1 = *(const float4*)&Cs[dd][tx * 8 + 4];
            float a[8] = {a0.x, a0.y, a0.z, a0.w, a1.x, a1.y, a1.z, a1.w};
            float b[8] = {b0.x, b0.y, b0.z, b0.w, b1.x, b1.y, b1.z, b1.w};
#pragma unroll
            for (int i = 0; i < 8; ++i)
#pragma unroll
                for (int j = 0; j < 8; ++j) acc[i][j] = fmaf(a[i], b[j], acc[i][j]);
        }
    }
    float cbnv[8];
#pragma unroll
    for (int j = 0; j < 8; ++j) cbnv[j] = cbn[k0 + tx * 8 + j];
#pragma unroll
    for (int i = 0; i < 8; ++i) {
        float bv = cbnv[0] - 2.f * acc[i][0];
        int bj = 0;
#pragma unroll
        for (int j = 1; j < 8; ++j) {
            float v = cbnv[j] - 2.f * acc[i][j];
            if (v < bv) { bv = v; bj = j; }
        }
        u64 p = ((u64)fkey(bv) << 32) | (unsigned)(k0 + tx * 8 + bj);
#pragma unroll
        for (int m = 8; m >= 1; m >>= 1) {
            u64 q = __shfl_xor(p, m);
            if (q < p) p = q;
        }
        if (tx == 0) atomicMin(&best[n0 + ty * 8 + i], p);
    }
}

__global__ void extract_idx(const unsigned long long* __restrict__ best,
                            int* __restrict__ idx) {
    int n = blockIdx.x * 256 + threadIdx.x;
    idx[n] = (int)(unsigned)(best[n] & 0xFFFFFFFFull);
}

// ---------------- gather + straight-through (float4) ----------------
__global__ void gather_kernel(const float* __restrict__ z, const float* __restrict__ cb,
                              const int* __restrict__ idx, float* __restrict__ out) {
    const int d = blockIdx.x;
    const float* cbrow = &cb[(size_t)d * NK];
    const float* zrow  = &z [(size_t)d * NK];
    float* st = &out[(size_t)d * NK];
    float* zq = &out[(size_t)D * NK + (size_t)d * NK];
    for (int n4 = threadIdx.x; n4 < NK / 4; n4 += 256) {
        int4 iv = *(const int4*)&idx[n4 * 4];
        float4 zv = *(const float4*)&zrow[n4 * 4];
        float4 q;
        q.x = cbrow[iv.x]; q.y = cbrow[iv.y]; q.z = cbrow[iv.z]; q.w = cbrow[iv.w];
        float4 stv;
        stv.x = q.x + (zv.x - q.x);
        stv.y = q.y + (zv.y - q.y);
        stv.z = q.z + (zv.z - q.z);
        stv.w = q.w + (zv.w - q.w);
        *(float4*)&st[n4 * 4] = stv;
        *(float4*)&zq[n4 * 4] = q;
    }
}

extern "C" void kernel_launch(void* const* d_in, const int* in_sizes, int n_in,
                              void* d_out, int out_size, void* d_ws, size_t ws_size,
                              hipStream_t stream) {
    const float* z  = (const float*)d_in[0];
    const float* cb = (const float*)d_in[1];
    float* out = (float*)d_out;
    char* ws = (char*)d_ws;

    const size_t oA  = 0;
    const size_t oB  = oA + (size_t)NK * KA * 2;
    const size_t oT  = oB + (size_t)NK * KB * 2;
    const size_t oI  = oT + (size_t)NK * 64 * 16;
    const size_t oR  = oI + NK * 4;
    const size_t oN  = oR + NK * 4;
    const size_t oP  = oN + 256;
    const size_t REQ = oP + (size_t)16 * NK * 4;

    if (ws_size >= REQ) {
        _Float16* Ap = (_Float16*)(ws + oA);
        _Float16* Bp = (_Float16*)(ws + oB);
        ulonglong2* tp = (ulonglong2*)(ws + oT);
        int* idx = (int*)(ws + oI);
        int* rescue = (int*)(ws + oR);
        int* ctr = (int*)(ws + oN);
        float* partial = (float*)(ws + oP);

        split_transpose<<<dim3(NK / 64, D / 64, 2), 256, 0, stream>>>(z, cb, Ap, Bp, partial, ctr);
        gemm_mfma<<<256, 256, 0, stream>>>(Ap, Bp, partial, tp);
        reduce_rows<<<64, 256, 0, stream>>>(tp, idx, rescue, ctr);
        rescue_kernel<<<1024, 256, 0, stream>>>(z, cb, tp, rescue, ctr, idx);
        gather_kernel<<<1024, 256, 0, stream>>>(z, cb, idx, out);
    } else {
        unsigned long long* best = (unsigned long long*)ws;
        float* cbn = (float*)(ws + NK * 8);
        int* idx = (int*)(ws + NK * 8 + NK * 4);
        hipMemsetAsync(best, 0xFF, NK * 8, stream);
        cbnorm_kernel<<<64, 256, 0, stream>>>(cb, cbn);
        gemm_argmin<<<dim3(NK / 128, NK / 128), 256, 0, stream>>>(z, cb, cbn, best);
        extract_idx<<<16, 256, 0, stream>>>(best, idx);
        gather_kernel<<<1024, 256, 0, stream>>>(z, cb, idx, out);
    }
}

// Round 8
// 80.207 us; speedup vs baseline: 1.6675x; 1.6675x over previous
//
#include <hip/hip_runtime.h>
#include <stdint.h>

#define D  1024
#define NK 4096
#define KA 1024   // A = z_hi fp16 (hi-only; rescue covers the error)
#define KB 1024   // B = cb_hi fp16
#define TAU 0.15f // flag margin: 21 sigma of hi*hi approx error
#define CW  0.12f // candidate window in rescue: ~17 sigma
#define MAXC 1024

// ---- 256x256 pipelined MFMA GEMM params (R1/R6 structure: best measured) ----
#define BK2 32
#define NT2 (KA / BK2)   // 32 k-tiles
#define NBUF 4           // 4 single-tile LDS buffers -> prefetch distance 2

typedef __attribute__((ext_vector_type(8))) _Float16 f16x8;
typedef __attribute__((ext_vector_type(4))) float f32x4;
typedef unsigned long long u64;

__device__ __forceinline__ uint32_t fkey(float f) {
    uint32_t b = __float_as_uint(f);
    return (b & 0x80000000u) ? ~b : (b | 0x80000000u);
}
__device__ __forceinline__ float unfkey(uint32_t u) {
    uint32_t b = (u & 0x80000000u) ? (u & 0x7fffffffu) : ~u;
    return __uint_as_float(b);
}
__device__ __forceinline__ u64 umin64(u64 a, u64 b) { return a < b ? a : b; }
__device__ __forceinline__ u64 umax64(u64 a, u64 b) { return a > b ? a : b; }

__device__ __forceinline__ void gload16(void* lds, const void* g) {
    __builtin_amdgcn_global_load_lds(
        (const __attribute__((address_space(1))) unsigned int*)g,
        (__attribute__((address_space(3))) unsigned int*)lds, 16, 0, 0);
}

// ---------------- cbnorm (fallback path only) ----------------
__global__ void cbnorm_kernel(const float* __restrict__ cb, float* __restrict__ cbn) {
    __shared__ float red[256];
    const int kk = threadIdx.x & 63;
    const int dc = threadIdx.x >> 6;
    const int k  = blockIdx.x * 64 + kk;
    float s = 0.f;
    for (int d = dc; d < D; d += 4) {
        float v = cb[d * NK + k];
        s = fmaf(v, v, s);
    }
    red[threadIdx.x] = s;
    __syncthreads();
    if (dc == 0) cbn[k] = (red[kk] + red[64 + kk]) + (red[128 + kk] + red[192 + kk]);
}

// ---------------- transpose + fp16 cast; cb branch also emits sumsq partials ----------------
// Also zeroes the rescue counter (block (0,0,0) thread 0) -> removes the memset dispatch.
__global__ __launch_bounds__(256) void split_transpose(
        const float* __restrict__ z, const float* __restrict__ cb,
        _Float16* __restrict__ Ap, _Float16* __restrict__ Bp,
        float* __restrict__ partial, int* __restrict__ ctr) {
    __shared__ float T[64][65];
    if (blockIdx.x == 0 && blockIdx.y == 0 && blockIdx.z == 0 && threadIdx.x == 0)
        *ctr = 0;
    const int isZ = (blockIdx.z == 0);
    const float* src = isZ ? z : cb;
    _Float16* dst = isZ ? Ap : Bp;
    const int n0 = blockIdx.x * 64, d0 = blockIdx.y * 64;
    const int t = threadIdx.x;
#pragma unroll
    for (int i = 0; i < 4; ++i) {
        int dl = (t >> 4) + i * 16;
        int nl = (t & 15) * 4;
        float4 v = *(const float4*)&src[(size_t)(d0 + dl) * NK + n0 + nl];
        T[dl][nl] = v.x; T[dl][nl + 1] = v.y; T[dl][nl + 2] = v.z; T[dl][nl + 3] = v.w;
    }
    __syncthreads();
    const int nr = t >> 2, dch = (t & 3) * 16;
    f16x8 h0, h1;
    float s = 0.f;
#pragma unroll
    for (int j = 0; j < 8; ++j) {
        float v = T[dch + j][nr];
        s = fmaf(v, v, s);
        h0[j] = (_Float16)v;
    }
#pragma unroll
    for (int j = 0; j < 8; ++j) {
        float v = T[dch + 8 + j][nr];
        s = fmaf(v, v, s);
        h1[j] = (_Float16)v;
    }
    size_t base = (size_t)(n0 + nr) * KA + d0 + dch;
    *(f16x8*)&dst[base]     = h0;
    *(f16x8*)&dst[base + 8] = h1;
    if (!isZ) {
        s += __shfl_xor(s, 1);
        s += __shfl_xor(s, 2);
        if ((t & 3) == 0) partial[(size_t)(d0 >> 6) * NK + n0 + nr] = s;
    }
}

// ---------------- 256x256 fp16 MFMA GEMM (R1/R6: counted-vmcnt pipeline, best measured) ----------------
// 8 waves (2M x 4N), wave output 128x64, acc[8][4]. 4 LDS tile-buffers (128 KB):
// compute tile t from buf[t&3], stage tile t+2 into buf[(t+2)&3] (last read t-2).
// End-of-tile wait = s_waitcnt vmcnt(4): tile t+1 landed, tile t+2 stays in flight.
// cbn is summed inline from the 16 partials in the epilogue (64 L2-hot loads/thread).
__global__ __launch_bounds__(512, 2) void gemm_mfma(
        const _Float16* __restrict__ Ap, const _Float16* __restrict__ Bp,
        const float* __restrict__ partial, ulonglong2* __restrict__ tp) {
    __shared__ _Float16 As[NBUF][256 * BK2];
    __shared__ _Float16 Bs[NBUF][256 * BK2];
    const int tid = threadIdx.x;
    // XCD chunking: 8 XCDs x 32 wgs; chunk = 4 n-tiles x 8 k-tiles (bijective for 256 wgs)
    const int xcd = blockIdx.x & 7, idx = blockIdx.x >> 3;
    const int n0 = ((xcd >> 1) * 4 + (idx >> 3)) * 256;
    const int k0 = ((xcd & 1) * 8 + (idx & 7)) * 256;
    const int w = tid >> 6, l = tid & 63;
    const int wr = w >> 2, wc = w & 3;
    const int fr = l & 15, fq = l >> 4;

    f32x4 acc[8][4] = {};

    const int srow = tid >> 2;
    const int swz = ((tid & 3) ^ ((tid >> 3) & 3)) * 8;
    const _Float16* gA0 = Ap + (size_t)(n0 + srow) * KA + swz;
    const _Float16* gA1 = Ap + (size_t)(n0 + 128 + srow) * KA + swz;
    const _Float16* gB0 = Bp + (size_t)(k0 + srow) * KB + swz;
    const _Float16* gB1 = Bp + (size_t)(k0 + 128 + srow) * KB + swz;
    const int rcol = (fq ^ ((fr >> 1) & 3)) * 8;   // swizzled read column (0-conflict, proven)

    // prologue: stage tiles 0 and 1; wait for tile 0 only (tile 1 stays in flight)
    gload16(&As[0][tid * 8],        gA0);
    gload16(&As[0][4096 + tid * 8], gA1);
    gload16(&Bs[0][tid * 8],        gB0);
    gload16(&Bs[0][4096 + tid * 8], gB1);
    gload16(&As[1][tid * 8],        gA0 + BK2);
    gload16(&As[1][4096 + tid * 8], gA1 + BK2);
    gload16(&Bs[1][tid * 8],        gB0 + BK2);
    gload16(&Bs[1][4096 + tid * 8], gB1 + BK2);
    asm volatile("s_waitcnt vmcnt(4)" ::: "memory");
    __builtin_amdgcn_s_barrier();
    asm volatile("" ::: "memory");

    for (int t = 0; t < NT2; ++t) {
        const int b = t & 3;
        const int pb = (t + 2) & 3;
        const _Float16* Ab = As[b];
        const _Float16* Bb = Bs[b];
        const bool st = (t + 2) < NT2;

        // ---- phase 0: B-frags + A rows 0..63 of wave band; stage A of tile t+2 ----
        f16x8 bbf[4], a0[4];
#pragma unroll
        for (int ni = 0; ni < 4; ++ni)
            bbf[ni] = *(const f16x8*)&Bb[(wc * 64 + ni * 16 + fr) * BK2 + rcol];
#pragma unroll
        for (int mi = 0; mi < 4; ++mi)
            a0[mi] = *(const f16x8*)&Ab[(wr * 128 + mi * 16 + fr) * BK2 + rcol];
        if (st) {
            gload16(&As[pb][tid * 8],        gA0 + (t + 2) * BK2);
            gload16(&As[pb][4096 + tid * 8], gA1 + (t + 2) * BK2);
        }
        __builtin_amdgcn_s_setprio(1);
#pragma unroll
        for (int mi = 0; mi < 4; ++mi)
#pragma unroll
            for (int ni = 0; ni < 4; ++ni)
                acc[mi][ni] = __builtin_amdgcn_mfma_f32_16x16x32_f16(a0[mi], bbf[ni], acc[mi][ni], 0, 0, 0);
        __builtin_amdgcn_s_setprio(0);
        __builtin_amdgcn_s_barrier();

        // ---- phase 1: A rows 64..127 of wave band; stage B of tile t+2 ----
        f16x8 a1[4];
#pragma unroll
        for (int mi = 0; mi < 4; ++mi)
            a1[mi] = *(const f16x8*)&Ab[(wr * 128 + 64 + mi * 16 + fr) * BK2 + rcol];
        if (st) {
            gload16(&Bs[pb][tid * 8],        gB0 + (t + 2) * BK2);
            gload16(&Bs[pb][4096 + tid * 8], gB1 + (t + 2) * BK2);
        }
        __builtin_amdgcn_s_setprio(1);
#pragma unroll
        for (int mi = 0; mi < 4; ++mi)
#pragma unroll
            for (int ni = 0; ni < 4; ++ni)
                acc[4 + mi][ni] = __builtin_amdgcn_mfma_f32_16x16x32_f16(a1[mi], bbf[ni], acc[4 + mi][ni], 0, 0, 0);
        __builtin_amdgcn_s_setprio(0);

        // ---- tile boundary: counted wait (never 0 until the pipeline drains) ----
        if (t < NT2 - 2) {
            asm volatile("s_waitcnt vmcnt(4)" ::: "memory");
        } else if (t == NT2 - 2) {
            asm volatile("s_waitcnt vmcnt(0)" ::: "memory");
        }
        if (t < NT2 - 1) {
            __builtin_amdgcn_s_barrier();
            asm volatile("" ::: "memory");
        }
    }

    // ---- epilogue: inline cbn (16 partials, fixed order) + float-domain best2.
    // Exact ties imply gap < TAU -> flagged -> rescue recomputes in fp32 with
    // u64 smallest-k tie-breaking, so reference argmin semantics are preserved.
    float cbv[4];
#pragma unroll
    for (int ni = 0; ni < 4; ++ni) {
        const int k = k0 + wc * 64 + ni * 16 + fr;
        float s = 0.f;
#pragma unroll
        for (int j = 0; j < 16; ++j) s += partial[(size_t)j * NK + k];
        cbv[ni] = s;
    }
    const int kt64 = (k0 >> 6) + wc;
#pragma unroll
    for (int mi = 0; mi < 8; ++mi) {
#pragma unroll
        for (int reg = 0; reg < 4; ++reg) {
            float b1f = 1e30f, b2f = 1e30f;
            int b1k = 0;
#pragma unroll
            for (int ni = 0; ni < 4; ++ni) {
                float s = fmaf(-2.f, acc[mi][ni][reg], cbv[ni]);
                b2f = fminf(fmaxf(s, b1f), b2f);   // med3: new 2nd-best
                if (s < b1f) { b1f = s; b1k = k0 + wc * 64 + ni * 16 + fr; }
            }
#pragma unroll
            for (int m = 8; m >= 1; m >>= 1) {
                float q1 = __shfl_xor(b1f, m);
                int   qk = __shfl_xor(b1k, m);
                float q2 = __shfl_xor(b2f, m);
                b2f = fminf(fminf(b2f, q2), fmaxf(b1f, q1));
                if (q1 < b1f) { b1f = q1; b1k = qk; }
            }
            if (fr == 0) {
                int n = n0 + wr * 128 + mi * 16 + fq * 4 + reg;
                ulonglong2 v;
                v.x = ((u64)fkey(b1f) << 32) | (unsigned)b1k;
                v.y = ((u64)fkey(b2f) << 32) | 0xffffffffu;
                tp[(size_t)kt64 * NK + n] = v;
            }
        }
    }
}

// ---------------- reduce 64 groups/token (4 stripes + LDS merge); flag near-ties ----------------
__global__ __launch_bounds__(256) void reduce_rows(
        const ulonglong2* __restrict__ tp, int* __restrict__ idx,
        int* __restrict__ rescue, int* __restrict__ ctr) {
    __shared__ ulonglong2 sh[4][64];
    const int no = threadIdx.x & 63, st = threadIdx.x >> 6;
    const int n = blockIdx.x * 64 + no;
    u64 b1 = ~0ull, b2 = ~0ull;
#pragma unroll 4
    for (int g = st * 16; g < st * 16 + 16; ++g) {
        ulonglong2 e = tp[(size_t)g * NK + n];
        u64 nb1 = umin64(b1, e.x);
        u64 nb2 = umin64(umax64(b1, e.x), umin64(b2, e.y));
        b1 = nb1; b2 = nb2;
    }
    ulonglong2 v; v.x = b1; v.y = b2;
    sh[st][no] = v;
    __syncthreads();
    if (st == 0) {
#pragma unroll
        for (int j = 1; j < 4; ++j) {
            ulonglong2 e = sh[j][no];
            u64 nb1 = umin64(b1, e.x);
            u64 nb2 = umin64(umax64(b1, e.x), umin64(b2, e.y));
            b1 = nb1; b2 = nb2;
        }
        idx[n] = (int)(b1 & 0xffffffffull);
        float f1 = unfkey((uint32_t)(b1 >> 32));
        float f2 = unfkey((uint32_t)(b2 >> 32));
        if (f2 - f1 < TAU) {
            int p = atomicAdd(ctr, 1);
            rescue[p] = n;
        }
    }
}

// ---------------- candidate-pruned exact fp32 rescore; writes idx directly ----------------
__global__ __launch_bounds__(256) void rescue_kernel(
        const float* __restrict__ z, const float* __restrict__ cb,
        const ulonglong2* __restrict__ tp, const int* __restrict__ rescue,
        const int* __restrict__ ctr, int* __restrict__ idx) {
    const int cnt = min(*ctr, NK);
    const int tid = threadIdx.x;
    const int lane = tid & 63, wv = tid >> 6;

    __shared__ float zn[D];
    __shared__ int cand[MAXC];
    __shared__ int ccnt, overflow;
    __shared__ u64 wred[4];

    for (int slot = blockIdx.x; slot < cnt; slot += gridDim.x) {
        const int n = rescue[slot];
        if (tid == 0) { ccnt = 0; overflow = 0; }
        for (int d = tid; d < D; d += 256) zn[d] = z[(size_t)d * NK + n];

        if (tid < 64) {   // wave 0: build candidate list
            ulonglong2 e = tp[(size_t)tid * NK + n];
            u64 m = e.x;
#pragma unroll
            for (int msk = 32; msk >= 1; msk >>= 1) m = umin64(m, __shfl_xor(m, msk));
            const float thr = unfkey((uint32_t)(m >> 32)) + CW;
            if (unfkey((uint32_t)(e.y >> 32)) < thr) {
                int p = atomicAdd(&ccnt, 64);
                if (p + 64 <= MAXC) {
                    for (int j = 0; j < 64; ++j) cand[p + j] = tid * 64 + j;
                } else overflow = 1;
            } else if (unfkey((uint32_t)(e.x >> 32)) < thr) {
                int p = atomicAdd(&ccnt, 1);
                if (p < MAXC) cand[p] = (int)(e.x & 0xffffffffull);
                else overflow = 1;
            }
        }
        __syncthreads();

        const int ovf = overflow;
        const int m = ovf ? NK : min(ccnt, MAXC);
        u64 best = ~0ull;
        for (int ci = wv; ci < m; ci += 4) {
            const int k = ovf ? ci : cand[ci];
            float s = 0.f, s2 = 0.f;
#pragma unroll
            for (int j = 0; j < 16; ++j) {
                float c = cb[(size_t)(lane + j * 64) * NK + k];
                s  = fmaf(zn[lane + j * 64], c, s);
                s2 = fmaf(c, c, s2);
            }
#pragma unroll
            for (int msk = 32; msk >= 1; msk >>= 1) {
                s  += __shfl_xor(s, msk);
                s2 += __shfl_xor(s2, msk);
            }
            float sc = s2 - 2.f * s;
            best = umin64(best, ((u64)fkey(sc) << 32) | (unsigned)k);
        }
        if (lane == 0) wred[wv] = best;
        __syncthreads();
        if (tid == 0)
            idx[n] = (int)(umin64(umin64(wred[0], wred[1]),
                                  umin64(wred[2], wred[3])) & 0xffffffffull);
        __syncthreads();   // protect zn/cand/ccnt reuse on the next strided slot
    }
}

// ---------------- fallback fp32 VALU GEMM (round-1, for small ws) ----------------
__global__ __launch_bounds__(256) void gemm_argmin(
        const float* __restrict__ z, const float* __restrict__ cb,
        const float* __restrict__ cbn, unsigned long long* __restrict__ best) {
    __shared__ float Zs[8][128];
    __shared__ float Cs[8][128];
    const int n0 = blockIdx.y * 128, k0 = blockIdx.x * 128;
    const int tid = threadIdx.x;
    const int tx = tid & 15, ty = tid >> 4;
    const int lr = tid >> 5, lc = (tid & 31) << 2;
    float acc[8][8];
#pragma unroll
    for (int i = 0; i < 8; ++i)
#pragma unroll
        for (int j = 0; j < 8; ++j) acc[i][j] = 0.f;
    for (int d0 = 0; d0 < D; d0 += 8) {
        float4 zv = *(const float4*)&z [(d0 + lr) * NK + n0 + lc];
        float4 cv = *(const float4*)&cb[(d0 + lr) * NK + k0 + lc];
        __syncthreads();
        *(float4*)&Zs[lr][lc] = zv;
        *(float4*)&Cs[lr][lc] = cv;
        __syncthreads();
#pragma unroll
        for (int dd = 0; dd < 8; ++dd) {
            float4 a0 = *(const float4*)&Zs[dd][ty * 8];
            float4 a1 = *(const float4*)&Zs[dd][ty * 8 + 4];
            float4 b0 = *(const float4*)&Cs[dd][tx * 8];
            float4 b1 = *(const float4*)&Cs[dd][tx * 8 + 4];
            float a[8] = {a0.x, a0.y, a0.z, a0.w, a1.x, a1.y, a1.z, a1.w};
            float b[8] = {b0.x, b0.y, b0.z, b0.w, b1.x, b1.y, b1.z, b1.w};
#pragma unroll
            for (int i = 0; i < 8; ++i)
#pragma unroll
                for (int j = 0; j < 8; ++j) acc[i][j] = fmaf(a[i], b[j], acc[i][j]);
        }
    }
    float cbnv[8];
#pragma unroll
    for (int j = 0; j < 8; ++j) cbnv[j] = cbn[k0 + tx * 8 + j];
#pragma unroll
    for (int i = 0; i < 8; ++i) {
        float bv = cbnv[0] - 2.f * acc[i][0];
        int bj = 0;
#pragma unroll
        for (int j = 1; j < 8; ++j) {
            float v = cbnv[j] - 2.f * acc[i][j];
            if (v < bv) { bv = v; bj = j; }
        }
        u64 p = ((u64)fkey(bv) << 32) | (unsigned)(k0 + tx * 8 + bj);
#pragma unroll
        for (int m = 8; m >= 1; m >>= 1) {
            u64 q = __shfl_xor(p, m);
            if (q < p) p = q;
        }
        if (tx == 0) atomicMin(&best[n0 + ty * 8 + i], p);
    }
}

__global__ void extract_idx(const unsigned long long* __restrict__ best,
                            int* __restrict__ idx) {
    int n = blockIdx.x * 256 + threadIdx.x;
    idx[n] = (int)(unsigned)(best[n] & 0xFFFFFFFFull);
}

// ---------------- gather + straight-through (float4) ----------------
__global__ void gather_kernel(const float* __restrict__ z, const float* __restrict__ cb,
                              const int* __restrict__ idx, float* __restrict__ out) {
    const int d = blockIdx.x;
    const float* cbrow = &cb[(size_t)d * NK];
    const float* zrow  = &z [(size_t)d * NK];
    float* st = &out[(size_t)d * NK];
    float* zq = &out[(size_t)D * NK + (size_t)d * NK];
    for (int n4 = threadIdx.x; n4 < NK / 4; n4 += 256) {
        int4 iv = *(const int4*)&idx[n4 * 4];
        float4 zv = *(const float4*)&zrow[n4 * 4];
        float4 q;
        q.x = cbrow[iv.x]; q.y = cbrow[iv.y]; q.z = cbrow[iv.z]; q.w = cbrow[iv.w];
        float4 stv;
        stv.x = q.x + (zv.x - q.x);
        stv.y = q.y + (zv.y - q.y);
        stv.z = q.z + (zv.z - q.z);
        stv.w = q.w + (zv.w - q.w);
        *(float4*)&st[n4 * 4] = stv;
        *(float4*)&zq[n4 * 4] = q;
    }
}

extern "C" void kernel_launch(void* const* d_in, const int* in_sizes, int n_in,
                              void* d_out, int out_size, void* d_ws, size_t ws_size,
                              hipStream_t stream) {
    const float* z  = (const float*)d_in[0];
    const float* cb = (const float*)d_in[1];
    float* out = (float*)d_out;
    char* ws = (char*)d_ws;

    const size_t oA  = 0;
    const size_t oB  = oA + (size_t)NK * KA * 2;
    const size_t oT  = oB + (size_t)NK * KB * 2;
    const size_t oI  = oT + (size_t)NK * 64 * 16;
    const size_t oR  = oI + NK * 4;
    const size_t oN  = oR + NK * 4;
    const size_t oP  = oN + 256;
    const size_t REQ = oP + (size_t)16 * NK * 4;

    if (ws_size >= REQ) {
        _Float16* Ap = (_Float16*)(ws + oA);
        _Float16* Bp = (_Float16*)(ws + oB);
        ulonglong2* tp = (ulonglong2*)(ws + oT);
        int* idx = (int*)(ws + oI);
        int* rescue = (int*)(ws + oR);
        int* ctr = (int*)(ws + oN);
        float* partial = (float*)(ws + oP);

        split_transpose<<<dim3(NK / 64, D / 64, 2), 256, 0, stream>>>(z, cb, Ap, Bp, partial, ctr);
        gemm_mfma<<<256, 512, 0, stream>>>(Ap, Bp, partial, tp);
        reduce_rows<<<64, 256, 0, stream>>>(tp, idx, rescue, ctr);
        rescue_kernel<<<256, 256, 0, stream>>>(z, cb, tp, rescue, ctr, idx);
        gather_kernel<<<1024, 256, 0, stream>>>(z, cb, idx, out);
    } else {
        unsigned long long* best = (unsigned long long*)ws;
        float* cbn = (float*)(ws + NK * 8);
        int* idx = (int*)(ws + NK * 8 + NK * 4);
        hipMemsetAsync(best, 0xFF, NK * 8, stream);
        cbnorm_kernel<<<64, 256, 0, stream>>>(cb, cbn);
        gemm_argmin<<<dim3(NK / 128, NK / 128), 256, 0, stream>>>(z, cb, cbn, best);
        extract_idx<<<16, 256, 0, stream>>>(best, idx);
        gather_kernel<<<1024, 256, 0, stream>>>(z, cb, idx, out);
    }
}

// Round 9
// 79.636 us; speedup vs baseline: 1.6794x; 1.0072x over previous
//
#include <hip/hip_runtime.h>
#include <stdint.h>

#define D  1024
#define NK 4096
#define KA 1024   // A = z_hi fp16 (hi-only; rescue covers the error)
#define KB 1024   // B = cb_hi fp16
#define TAU 0.15f // flag margin: 21 sigma of hi*hi approx error
#define CW  0.12f // candidate window in rescue: ~17 sigma
#define MAXC 1024

// ---- 256x256 pipelined MFMA GEMM params (R1/R6 structure, mid-tile barrier removed) ----
#define BK2 32
#define NT2 (KA / BK2)   // 32 k-tiles
#define NBUF 4           // 4 single-tile LDS buffers -> prefetch distance 2

typedef __attribute__((ext_vector_type(8))) _Float16 f16x8;
typedef __attribute__((ext_vector_type(4))) float f32x4;
typedef unsigned long long u64;

__device__ __forceinline__ uint32_t fkey(float f) {
    uint32_t b = __float_as_uint(f);
    return (b & 0x80000000u) ? ~b : (b | 0x80000000u);
}
__device__ __forceinline__ float unfkey(uint32_t u) {
    uint32_t b = (u & 0x80000000u) ? (u & 0x7fffffffu) : ~u;
    return __uint_as_float(b);
}
__device__ __forceinline__ u64 umin64(u64 a, u64 b) { return a < b ? a : b; }
__device__ __forceinline__ u64 umax64(u64 a, u64 b) { return a > b ? a : b; }

__device__ __forceinline__ void gload16(void* lds, const void* g) {
    __builtin_amdgcn_global_load_lds(
        (const __attribute__((address_space(1))) unsigned int*)g,
        (__attribute__((address_space(3))) unsigned int*)lds, 16, 0, 0);
}

// ---------------- cbnorm (fallback path only) ----------------
__global__ void cbnorm_kernel(const float* __restrict__ cb, float* __restrict__ cbn) {
    __shared__ float red[256];
    const int kk = threadIdx.x & 63;
    const int dc = threadIdx.x >> 6;
    const int k  = blockIdx.x * 64 + kk;
    float s = 0.f;
    for (int d = dc; d < D; d += 4) {
        float v = cb[d * NK + k];
        s = fmaf(v, v, s);
    }
    red[threadIdx.x] = s;
    __syncthreads();
    if (dc == 0) cbn[k] = (red[kk] + red[64 + kk]) + (red[128 + kk] + red[192 + kk]);
}

// ---------------- transpose + fp16 cast; cb branch also emits sumsq partials ----------------
// Also zeroes the rescue counter (block (0,0,0) thread 0) -> removes the memset dispatch.
__global__ __launch_bounds__(256) void split_transpose(
        const float* __restrict__ z, const float* __restrict__ cb,
        _Float16* __restrict__ Ap, _Float16* __restrict__ Bp,
        float* __restrict__ partial, int* __restrict__ ctr) {
    __shared__ float T[64][65];
    if (blockIdx.x == 0 && blockIdx.y == 0 && blockIdx.z == 0 && threadIdx.x == 0)
        *ctr = 0;
    const int isZ = (blockIdx.z == 0);
    const float* src = isZ ? z : cb;
    _Float16* dst = isZ ? Ap : Bp;
    const int n0 = blockIdx.x * 64, d0 = blockIdx.y * 64;
    const int t = threadIdx.x;
#pragma unroll
    for (int i = 0; i < 4; ++i) {
        int dl = (t >> 4) + i * 16;
        int nl = (t & 15) * 4;
        float4 v = *(const float4*)&src[(size_t)(d0 + dl) * NK + n0 + nl];
        T[dl][nl] = v.x; T[dl][nl + 1] = v.y; T[dl][nl + 2] = v.z; T[dl][nl + 3] = v.w;
    }
    __syncthreads();
    const int nr = t >> 2, dch = (t & 3) * 16;
    f16x8 h0, h1;
    float s = 0.f;
#pragma unroll
    for (int j = 0; j < 8; ++j) {
        float v = T[dch + j][nr];
        s = fmaf(v, v, s);
        h0[j] = (_Float16)v;
    }
#pragma unroll
    for (int j = 0; j < 8; ++j) {
        float v = T[dch + 8 + j][nr];
        s = fmaf(v, v, s);
        h1[j] = (_Float16)v;
    }
    size_t base = (size_t)(n0 + nr) * KA + d0 + dch;
    *(f16x8*)&dst[base]     = h0;
    *(f16x8*)&dst[base + 8] = h1;
    if (!isZ) {
        s += __shfl_xor(s, 1);
        s += __shfl_xor(s, 2);
        if ((t & 3) == 0) partial[(size_t)(d0 >> 6) * NK + n0 + nr] = s;
    }
}

// ---------------- 256x256 fp16 MFMA GEMM: counted-vmcnt pipeline, 1 barrier/tile ----------------
// 8 waves (2M x 4N), wave output 128x64, acc[8][4]. 4 LDS tile-buffers (128 KB):
// compute tile t from buf[t&3], stage tile t+2 into buf[(t+2)&3] (last read t-2).
// CHANGE vs R1/R8: the mid-tile barrier is REMOVED. It protected nothing (phase1
// reads the same buffer, read-read; the stage-vs-read hazard on buf[pb] is covered
// by >=2 tile-end barriers + the counted vmcnt). One barrier per tile doubles the
// compiler's fine-grained lgkm-interleave window (32 MFMA + 12 ds_read + 6 gload)
// and halves rendezvous events. NO lgkmcnt(0)/sched_barrier rendezvous -- R2/R3
// proved forcing all reads to complete before the first MFMA kills the compiler's
// JIT partial-lgkm interleave (the mechanism that makes R1 the family's best).
// End-of-tile wait = s_waitcnt vmcnt(4): tile t+1 landed, tile t+2 stays in flight.
// cbn is summed inline from the 16 partials in the epilogue (64 L2-hot loads/thread).
__global__ __launch_bounds__(512, 2) void gemm_mfma(
        const _Float16* __restrict__ Ap, const _Float16* __restrict__ Bp,
        const float* __restrict__ partial, ulonglong2* __restrict__ tp) {
    __shared__ _Float16 As[NBUF][256 * BK2];
    __shared__ _Float16 Bs[NBUF][256 * BK2];
    const int tid = threadIdx.x;
    // XCD chunking: 8 XCDs x 32 wgs; chunk = 4 n-tiles x 8 k-tiles (bijective for 256 wgs)
    const int xcd = blockIdx.x & 7, idx = blockIdx.x >> 3;
    const int n0 = ((xcd >> 1) * 4 + (idx >> 3)) * 256;
    const int k0 = ((xcd & 1) * 8 + (idx & 7)) * 256;
    const int w = tid >> 6, l = tid & 63;
    const int wr = w >> 2, wc = w & 3;
    const int fr = l & 15, fq = l >> 4;

    f32x4 acc[8][4] = {};

    const int srow = tid >> 2;
    const int swz = ((tid & 3) ^ ((tid >> 3) & 3)) * 8;
    const _Float16* gA0 = Ap + (size_t)(n0 + srow) * KA + swz;
    const _Float16* gA1 = Ap + (size_t)(n0 + 128 + srow) * KA + swz;
    const _Float16* gB0 = Bp + (size_t)(k0 + srow) * KB + swz;
    const _Float16* gB1 = Bp + (size_t)(k0 + 128 + srow) * KB + swz;
    const int rcol = (fq ^ ((fr >> 1) & 3)) * 8;   // swizzled read column (0-conflict, proven)

    // prologue: stage tiles 0 and 1; wait for tile 0 only (tile 1 stays in flight)
    gload16(&As[0][tid * 8],        gA0);
    gload16(&As[0][4096 + tid * 8], gA1);
    gload16(&Bs[0][tid * 8],        gB0);
    gload16(&Bs[0][4096 + tid * 8], gB1);
    gload16(&As[1][tid * 8],        gA0 + BK2);
    gload16(&As[1][4096 + tid * 8], gA1 + BK2);
    gload16(&Bs[1][tid * 8],        gB0 + BK2);
    gload16(&Bs[1][4096 + tid * 8], gB1 + BK2);
    asm volatile("s_waitcnt vmcnt(4)" ::: "memory");
    __builtin_amdgcn_s_barrier();
    asm volatile("" ::: "memory");

    for (int t = 0; t < NT2; ++t) {
        const int b = t & 3;
        const int pb = (t + 2) & 3;
        const _Float16* Ab = As[b];
        const _Float16* Bb = Bs[b];
        const bool st = (t + 2) < NT2;

        // ---- phase 0: B-frags + A rows 0..63 of wave band; stage A of tile t+2 ----
        f16x8 bbf[4], a0[4];
#pragma unroll
        for (int ni = 0; ni < 4; ++ni)
            bbf[ni] = *(const f16x8*)&Bb[(wc * 64 + ni * 16 + fr) * BK2 + rcol];
#pragma unroll
        for (int mi = 0; mi < 4; ++mi)
            a0[mi] = *(const f16x8*)&Ab[(wr * 128 + mi * 16 + fr) * BK2 + rcol];
        if (st) {
            gload16(&As[pb][tid * 8],        gA0 + (t + 2) * BK2);
            gload16(&As[pb][4096 + tid * 8], gA1 + (t + 2) * BK2);
        }
        __builtin_amdgcn_s_setprio(1);
#pragma unroll
        for (int mi = 0; mi < 4; ++mi)
#pragma unroll
            for (int ni = 0; ni < 4; ++ni)
                acc[mi][ni] = __builtin_amdgcn_mfma_f32_16x16x32_f16(a0[mi], bbf[ni], acc[mi][ni], 0, 0, 0);
        __builtin_amdgcn_s_setprio(0);
        // (mid-tile barrier removed -- no hazard; see header comment)

        // ---- phase 1: A rows 64..127 of wave band; stage B of tile t+2 ----
        f16x8 a1[4];
#pragma unroll
        for (int mi = 0; mi < 4; ++mi)
            a1[mi] = *(const f16x8*)&Ab[(wr * 128 + 64 + mi * 16 + fr) * BK2 + rcol];
        if (st) {
            gload16(&Bs[pb][tid * 8],        gB0 + (t + 2) * BK2);
            gload16(&Bs[pb][4096 + tid * 8], gB1 + (t + 2) * BK2);
        }
        __builtin_amdgcn_s_setprio(1);
#pragma unroll
        for (int mi = 0; mi < 4; ++mi)
#pragma unroll
            for (int ni = 0; ni < 4; ++ni)
                acc[4 + mi][ni] = __builtin_amdgcn_mfma_f32_16x16x32_f16(a1[mi], bbf[ni], acc[4 + mi][ni], 0, 0, 0);
        __builtin_amdgcn_s_setprio(0);

        // ---- tile boundary: counted wait (never 0 until the pipeline drains) ----
        if (t < NT2 - 2) {
            asm volatile("s_waitcnt vmcnt(4)" ::: "memory");
        } else if (t == NT2 - 2) {
            asm volatile("s_waitcnt vmcnt(0)" ::: "memory");
        }
        if (t < NT2 - 1) {
            __builtin_amdgcn_s_barrier();
            asm volatile("" ::: "memory");
        }
    }

    // ---- epilogue: inline cbn (16 partials, fixed order) + float-domain best2.
    // Exact ties imply gap < TAU -> flagged -> rescue recomputes in fp32 with
    // u64 smallest-k tie-breaking, so reference argmin semantics are preserved.
    float cbv[4];
#pragma unroll
    for (int ni = 0; ni < 4; ++ni) {
        const int k = k0 + wc * 64 + ni * 16 + fr;
        float s = 0.f;
#pragma unroll
        for (int j = 0; j < 16; ++j) s += partial[(size_t)j * NK + k];
        cbv[ni] = s;
    }
    const int kt64 = (k0 >> 6) + wc;
#pragma unroll
    for (int mi = 0; mi < 8; ++mi) {
#pragma unroll
        for (int reg = 0; reg < 4; ++reg) {
            float b1f = 1e30f, b2f = 1e30f;
            int b1k = 0;
#pragma unroll
            for (int ni = 0; ni < 4; ++ni) {
                float s = fmaf(-2.f, acc[mi][ni][reg], cbv[ni]);
                b2f = fminf(fmaxf(s, b1f), b2f);   // med3: new 2nd-best
                if (s < b1f) { b1f = s; b1k = k0 + wc * 64 + ni * 16 + fr; }
            }
#pragma unroll
            for (int m = 8; m >= 1; m >>= 1) {
                float q1 = __shfl_xor(b1f, m);
                int   qk = __shfl_xor(b1k, m);
                float q2 = __shfl_xor(b2f, m);
                b2f = fminf(fminf(b2f, q2), fmaxf(b1f, q1));
                if (q1 < b1f) { b1f = q1; b1k = qk; }
            }
            if (fr == 0) {
                int n = n0 + wr * 128 + mi * 16 + fq * 4 + reg;
                ulonglong2 v;
                v.x = ((u64)fkey(b1f) << 32) | (unsigned)b1k;
                v.y = ((u64)fkey(b2f) << 32) | 0xffffffffu;
                tp[(size_t)kt64 * NK + n] = v;
            }
        }
    }
}

// ---------------- reduce 64 groups/token (4 stripes + LDS merge); flag near-ties ----------------
__global__ __launch_bounds__(256) void reduce_rows(
        const ulonglong2* __restrict__ tp, int* __restrict__ idx,
        int* __restrict__ rescue, int* __restrict__ ctr) {
    __shared__ ulonglong2 sh[4][64];
    const int no = threadIdx.x & 63, st = threadIdx.x >> 6;
    const int n = blockIdx.x * 64 + no;
    u64 b1 = ~0ull, b2 = ~0ull;
#pragma unroll 4
    for (int g = st * 16; g < st * 16 + 16; ++g) {
        ulonglong2 e = tp[(size_t)g * NK + n];
        u64 nb1 = umin64(b1, e.x);
        u64 nb2 = umin64(umax64(b1, e.x), umin64(b2, e.y));
        b1 = nb1; b2 = nb2;
    }
    ulonglong2 v; v.x = b1; v.y = b2;
    sh[st][no] = v;
    __syncthreads();
    if (st == 0) {
#pragma unroll
        for (int j = 1; j < 4; ++j) {
            ulonglong2 e = sh[j][no];
            u64 nb1 = umin64(b1, e.x);
            u64 nb2 = umin64(umax64(b1, e.x), umin64(b2, e.y));
            b1 = nb1; b2 = nb2;
        }
        idx[n] = (int)(b1 & 0xffffffffull);
        float f1 = unfkey((uint32_t)(b1 >> 32));
        float f2 = unfkey((uint32_t)(b2 >> 32));
        if (f2 - f1 < TAU) {
            int p = atomicAdd(ctr, 1);
            rescue[p] = n;
        }
    }
}

// ---------------- candidate-pruned exact fp32 rescore; writes idx directly ----------------
__global__ __launch_bounds__(256) void rescue_kernel(
        const float* __restrict__ z, const float* __restrict__ cb,
        const ulonglong2* __restrict__ tp, const int* __restrict__ rescue,
        const int* __restrict__ ctr, int* __restrict__ idx) {
    const int cnt = min(*ctr, NK);
    const int tid = threadIdx.x;
    const int lane = tid & 63, wv = tid >> 6;

    __shared__ float zn[D];
    __shared__ int cand[MAXC];
    __shared__ int ccnt, overflow;
    __shared__ u64 wred[4];

    for (int slot = blockIdx.x; slot < cnt; slot += gridDim.x) {
        const int n = rescue[slot];
        if (tid == 0) { ccnt = 0; overflow = 0; }
        for (int d = tid; d < D; d += 256) zn[d] = z[(size_t)d * NK + n];

        if (tid < 64) {   // wave 0: build candidate list
            ulonglong2 e = tp[(size_t)tid * NK + n];
            u64 m = e.x;
#pragma unroll
            for (int msk = 32; msk >= 1; msk >>= 1) m = umin64(m, __shfl_xor(m, msk));
            const float thr = unfkey((uint32_t)(m >> 32)) + CW;
            if (unfkey((uint32_t)(e.y >> 32)) < thr) {
                int p = atomicAdd(&ccnt, 64);
                if (p + 64 <= MAXC) {
                    for (int j = 0; j < 64; ++j) cand[p + j] = tid * 64 + j;
                } else overflow = 1;
            } else if (unfkey((uint32_t)(e.x >> 32)) < thr) {
                int p = atomicAdd(&ccnt, 1);
                if (p < MAXC) cand[p] = (int)(e.x & 0xffffffffull);
                else overflow = 1;
            }
        }
        __syncthreads();

        const int ovf = overflow;
        const int m = ovf ? NK : min(ccnt, MAXC);
        u64 best = ~0ull;
        for (int ci = wv; ci < m; ci += 4) {
            const int k = ovf ? ci : cand[ci];
            float s = 0.f, s2 = 0.f;
#pragma unroll
            for (int j = 0; j < 16; ++j) {
                float c = cb[(size_t)(lane + j * 64) * NK + k];
                s  = fmaf(zn[lane + j * 64], c, s);
                s2 = fmaf(c, c, s2);
            }
#pragma unroll
            for (int msk = 32; msk >= 1; msk >>= 1) {
                s  += __shfl_xor(s, msk);
                s2 += __shfl_xor(s2, msk);
            }
            float sc = s2 - 2.f * s;
            best = umin64(best, ((u64)fkey(sc) << 32) | (unsigned)k);
        }
        if (lane == 0) wred[wv] = best;
        __syncthreads();
        if (tid == 0)
            idx[n] = (int)(umin64(umin64(wred[0], wred[1]),
                                  umin64(wred[2], wred[3])) & 0xffffffffull);
        __syncthreads();   // protect zn/cand/ccnt reuse on the next strided slot
    }
}

// ---------------- fallback fp32 VALU GEMM (round-1, for small ws) ----------------
__global__ __launch_bounds__(256) void gemm_argmin(
        const float* __restrict__ z, const float* __restrict__ cb,
        const float* __restrict__ cbn, unsigned long long* __restrict__ best) {
    __shared__ float Zs[8][128];
    __shared__ float Cs[8][128];
    const int n0 = blockIdx.y * 128, k0 = blockIdx.x * 128;
    const int tid = threadIdx.x;
    const int tx = tid & 15, ty = tid >> 4;
    const int lr = tid >> 5, lc = (tid & 31) << 2;
    float acc[8][8];
#pragma unroll
    for (int i = 0; i < 8; ++i)
#pragma unroll
        for (int j = 0; j < 8; ++j) acc[i][j] = 0.f;
    for (int d0 = 0; d0 < D; d0 += 8) {
        float4 zv = *(const float4*)&z [(d0 + lr) * NK + n0 + lc];
        float4 cv = *(const float4*)&cb[(d0 + lr) * NK + k0 + lc];
        __syncthreads();
        *(float4*)&Zs[lr][lc] = zv;
        *(float4*)&Cs[lr][lc] = cv;
        __syncthreads();
#pragma unroll
        for (int dd = 0; dd < 8; ++dd) {
            float4 a0 = *(const float4*)&Zs[dd][ty * 8];
            float4 a1 = *(const float4*)&Zs[dd][ty * 8 + 4];
            float4 b0 = *(const float4*)&Cs[dd][tx * 8];
            float4 b1 = *(const float4*)&Cs[dd][tx * 8 + 4];
            float a[8] = {a0.x, a0.y, a0.z, a0.w, a1.x, a1.y, a1.z, a1.w};
            float b[8] = {b0.x, b0.y, b0.z, b0.w, b1.x, b1.y, b1.z, b1.w};
#pragma unroll
            for (int i = 0; i < 8; ++i)
#pragma unroll
                for (int j = 0; j < 8; ++j) acc[i][j] = fmaf(a[i], b[j], acc[i][j]);
        }
    }
    float cbnv[8];
#pragma unroll
    for (int j = 0; j < 8; ++j) cbnv[j] = cbn[k0 + tx * 8 + j];
#pragma unroll
    for (int i = 0; i < 8; ++i) {
        float bv = cbnv[0] - 2.f * acc[i][0];
        int bj = 0;
#pragma unroll
        for (int j = 1; j < 8; ++j) {
            float v = cbnv[j] - 2.f * acc[i][j];
            if (v < bv) { bv = v; bj = j; }
        }
        u64 p = ((u64)fkey(bv) << 32) | (unsigned)(k0 + tx * 8 + bj);
#pragma unroll
        for (int m = 8; m >= 1; m >>= 1) {
            u64 q = __shfl_xor(p, m);
            if (q < p) p = q;
        }
        if (tx == 0) atomicMin(&best[n0 + ty * 8 + i], p);
    }
}

__global__ void extract_idx(const unsigned long long* __restrict__ best,
                            int* __restrict__ idx) {
    int n = blockIdx.x * 256 + threadIdx.x;
    idx[n] = (int)(unsigned)(best[n] & 0xFFFFFFFFull);
}

// ---------------- gather + straight-through (float4) ----------------
__global__ void gather_kernel(const float* __restrict__ z, const float* __restrict__ cb,
                              const int* __restrict__ idx, float* __restrict__ out) {
    const int d = blockIdx.x;
    const float* cbrow = &cb[(size_t)d * NK];
    const float* zrow  = &z [(size_t)d * NK];
    float* st = &out[(size_t)d * NK];
    float* zq = &out[(size_t)D * NK + (size_t)d * NK];
    for (int n4 = threadIdx.x; n4 < NK / 4; n4 += 256) {
        int4 iv = *(const int4*)&idx[n4 * 4];
        float4 zv = *(const float4*)&zrow[n4 * 4];
        float4 q;
        q.x = cbrow[iv.x]; q.y = cbrow[iv.y]; q.z = cbrow[iv.z]; q.w = cbrow[iv.w];
        float4 stv;
        stv.x = q.x + (zv.x - q.x);
        stv.y = q.y + (zv.y - q.y);
        stv.z = q.z + (zv.z - q.z);
        stv.w = q.w + (zv.w - q.w);
        *(float4*)&st[n4 * 4] = stv;
        *(float4*)&zq[n4 * 4] = q;
    }
}

extern "C" void kernel_launch(void* const* d_in, const int* in_sizes, int n_in,
                              void* d_out, int out_size, void* d_ws, size_t ws_size,
                              hipStream_t stream) {
    const float* z  = (const float*)d_in[0];
    const float* cb = (const float*)d_in[1];
    float* out = (float*)d_out;
    char* ws = (char*)d_ws;

    const size_t oA  = 0;
    const size_t oB  = oA + (size_t)NK * KA * 2;
    const size_t oT  = oB + (size_t)NK * KB * 2;
    const size_t oI  = oT + (size_t)NK * 64 * 16;
    const size_t oR  = oI + NK * 4;
    const size_t oN  = oR + NK * 4;
    const size_t oP  = oN + 256;
    const size_t REQ = oP + (size_t)16 * NK * 4;

    if (ws_size >= REQ) {
        _Float16* Ap = (_Float16*)(ws + oA);
        _Float16* Bp = (_Float16*)(ws + oB);
        ulonglong2* tp = (ulonglong2*)(ws + oT);
        int* idx = (int*)(ws + oI);
        int* rescue = (int*)(ws + oR);
        int* ctr = (int*)(ws + oN);
        float* partial = (float*)(ws + oP);

        split_transpose<<<dim3(NK / 64, D / 64, 2), 256, 0, stream>>>(z, cb, Ap, Bp, partial, ctr);
        gemm_mfma<<<256, 512, 0, stream>>>(Ap, Bp, partial, tp);
        reduce_rows<<<64, 256, 0, stream>>>(tp, idx, rescue, ctr);
        rescue_kernel<<<256, 256, 0, stream>>>(z, cb, tp, rescue, ctr, idx);
        gather_kernel<<<1024, 256, 0, stream>>>(z, cb, idx, out);
    } else {
        unsigned long long* best = (unsigned long long*)ws;
        float* cbn = (float*)(ws + NK * 8);
        int* idx = (int*)(ws + NK * 8 + NK * 4);
        hipMemsetAsync(best, 0xFF, NK * 8, stream);
        cbnorm_kernel<<<64, 256, 0, stream>>>(cb, cbn);
        gemm_argmin<<<dim3(NK / 128, NK / 128), 256, 0, stream>>>(z, cb, cbn, best);
        extract_idx<<<16, 256, 0, stream>>>(best, idx);
        gather_kernel<<<1024, 256, 0, stream>>>(z, cb, idx, out);
    }
}

// Round 11
// 79.369 us; speedup vs baseline: 1.6851x; 1.0034x over previous
//
#include <hip/hip_runtime.h>
#include <stdint.h>

#define D  1024
#define NK 4096
#define KA 1024   // A = z_hi fp16 (hi-only; rescue covers the error)
#define KB 1024   // B = cb_hi fp16
#define TAU 0.15f // flag margin: 21 sigma of hi*hi approx error
#define CW  0.12f // candidate window in rescue: ~17 sigma
#define MAXC 1024

// ---- 256x256 pipelined MFMA GEMM params (R9 structure: session best) ----
#define BK2 32
#define NT2 (KA / BK2)   // 32 k-tiles
#define NBUF 4           // 4 single-tile LDS buffers -> prefetch distance 2

typedef __attribute__((ext_vector_type(8))) _Float16 f16x8;
typedef __attribute__((ext_vector_type(4))) float f32x4;
typedef unsigned long long u64;

__device__ __forceinline__ uint32_t fkey(float f) {
    uint32_t b = __float_as_uint(f);
    return (b & 0x80000000u) ? ~b : (b | 0x80000000u);
}
__device__ __forceinline__ float unfkey(uint32_t u) {
    uint32_t b = (u & 0x80000000u) ? (u & 0x7fffffffu) : ~u;
    return __uint_as_float(b);
}
__device__ __forceinline__ u64 umin64(u64 a, u64 b) { return a < b ? a : b; }
__device__ __forceinline__ u64 umax64(u64 a, u64 b) { return a > b ? a : b; }

__device__ __forceinline__ void gload16(void* lds, const void* g) {
    __builtin_amdgcn_global_load_lds(
        (const __attribute__((address_space(1))) unsigned int*)g,
        (__attribute__((address_space(3))) unsigned int*)lds, 16, 0, 0);
}

// ---------------- cbnorm (fallback path only) ----------------
__global__ void cbnorm_kernel(const float* __restrict__ cb, float* __restrict__ cbn) {
    __shared__ float red[256];
    const int kk = threadIdx.x & 63;
    const int dc = threadIdx.x >> 6;
    const int k  = blockIdx.x * 64 + kk;
    float s = 0.f;
    for (int d = dc; d < D; d += 4) {
        float v = cb[d * NK + k];
        s = fmaf(v, v, s);
    }
    red[threadIdx.x] = s;
    __syncthreads();
    if (dc == 0) cbn[k] = (red[kk] + red[64 + kk]) + (red[128 + kk] + red[192 + kk]);
}

// ---------------- transpose + fp16 cast; cb branch also emits sumsq partials ----------------
// Also zeroes the rescue counter (block (0,0,0) thread 0) -> removes the memset dispatch.
__global__ __launch_bounds__(256) void split_transpose(
        const float* __restrict__ z, const float* __restrict__ cb,
        _Float16* __restrict__ Ap, _Float16* __restrict__ Bp,
        float* __restrict__ partial, int* __restrict__ ctr) {
    __shared__ float T[64][65];
    if (blockIdx.x == 0 && blockIdx.y == 0 && blockIdx.z == 0 && threadIdx.x == 0)
        *ctr = 0;
    const int isZ = (blockIdx.z == 0);
    const float* src = isZ ? z : cb;
    _Float16* dst = isZ ? Ap : Bp;
    const int n0 = blockIdx.x * 64, d0 = blockIdx.y * 64;
    const int t = threadIdx.x;
#pragma unroll
    for (int i = 0; i < 4; ++i) {
        int dl = (t >> 4) + i * 16;
        int nl = (t & 15) * 4;
        float4 v = *(const float4*)&src[(size_t)(d0 + dl) * NK + n0 + nl];
        T[dl][nl] = v.x; T[dl][nl + 1] = v.y; T[dl][nl + 2] = v.z; T[dl][nl + 3] = v.w;
    }
    __syncthreads();
    const int nr = t >> 2, dch = (t & 3) * 16;
    f16x8 h0, h1;
    float s = 0.f;
#pragma unroll
    for (int j = 0; j < 8; ++j) {
        float v = T[dch + j][nr];
        s = fmaf(v, v, s);
        h0[j] = (_Float16)v;
    }
#pragma unroll
    for (int j = 0; j < 8; ++j) {
        float v = T[dch + 8 + j][nr];
        s = fmaf(v, v, s);
        h1[j] = (_Float16)v;
    }
    size_t base = (size_t)(n0 + nr) * KA + d0 + dch;
    *(f16x8*)&dst[base]     = h0;
    *(f16x8*)&dst[base + 8] = h1;
    if (!isZ) {
        s += __shfl_xor(s, 1);
        s += __shfl_xor(s, 2);
        if ((t & 3) == 0) partial[(size_t)(d0 >> 6) * NK + n0 + nr] = s;
    }
}

// ---------------- 256x256 fp16 MFMA GEMM: counted-vmcnt pipeline, 1 barrier/tile ----------------
// 8 waves (2M x 4N), wave output 128x64, acc[8][4]. 4 LDS tile-buffers (128 KB):
// compute tile t from buf[t&3], stage tile t+2 into buf[(t+2)&3] (last read t-2).
// One barrier per tile; NO pre-MFMA lgkm rendezvous (R2/R3 proved it kills the
// compiler's fine-grained partial-lgkm interleave). End-of-tile wait = vmcnt(4):
// tile t+1 landed, tile t+2 stays in flight. cbn summed inline from partials.
__global__ __launch_bounds__(512, 2) void gemm_mfma(
        const _Float16* __restrict__ Ap, const _Float16* __restrict__ Bp,
        const float* __restrict__ partial, ulonglong2* __restrict__ tp) {
    __shared__ _Float16 As[NBUF][256 * BK2];
    __shared__ _Float16 Bs[NBUF][256 * BK2];
    const int tid = threadIdx.x;
    // XCD chunking: 8 XCDs x 32 wgs; chunk = 4 n-tiles x 8 k-tiles (bijective for 256 wgs)
    const int xcd = blockIdx.x & 7, idx = blockIdx.x >> 3;
    const int n0 = ((xcd >> 1) * 4 + (idx >> 3)) * 256;
    const int k0 = ((xcd & 1) * 8 + (idx & 7)) * 256;
    const int w = tid >> 6, l = tid & 63;
    const int wr = w >> 2, wc = w & 3;
    const int fr = l & 15, fq = l >> 4;

    f32x4 acc[8][4] = {};

    const int srow = tid >> 2;
    const int swz = ((tid & 3) ^ ((tid >> 3) & 3)) * 8;
    const _Float16* gA0 = Ap + (size_t)(n0 + srow) * KA + swz;
    const _Float16* gA1 = Ap + (size_t)(n0 + 128 + srow) * KA + swz;
    const _Float16* gB0 = Bp + (size_t)(k0 + srow) * KB + swz;
    const _Float16* gB1 = Bp + (size_t)(k0 + 128 + srow) * KB + swz;
    const int rcol = (fq ^ ((fr >> 1) & 3)) * 8;   // swizzled read column (0-conflict, proven)

    // prologue: stage tiles 0 and 1; wait for tile 0 only (tile 1 stays in flight)
    gload16(&As[0][tid * 8],        gA0);
    gload16(&As[0][4096 + tid * 8], gA1);
    gload16(&Bs[0][tid * 8],        gB0);
    gload16(&Bs[0][4096 + tid * 8], gB1);
    gload16(&As[1][tid * 8],        gA0 + BK2);
    gload16(&As[1][4096 + tid * 8], gA1 + BK2);
    gload16(&Bs[1][tid * 8],        gB0 + BK2);
    gload16(&Bs[1][4096 + tid * 8], gB1 + BK2);
    asm volatile("s_waitcnt vmcnt(4)" ::: "memory");
    __builtin_amdgcn_s_barrier();
    asm volatile("" ::: "memory");

    for (int t = 0; t < NT2; ++t) {
        const int b = t & 3;
        const int pb = (t + 2) & 3;
        const _Float16* Ab = As[b];
        const _Float16* Bb = Bs[b];
        const bool st = (t + 2) < NT2;

        // ---- phase 0: B-frags + A rows 0..63 of wave band; stage A of tile t+2 ----
        f16x8 bbf[4], a0[4];
#pragma unroll
        for (int ni = 0; ni < 4; ++ni)
            bbf[ni] = *(const f16x8*)&Bb[(wc * 64 + ni * 16 + fr) * BK2 + rcol];
#pragma unroll
        for (int mi = 0; mi < 4; ++mi)
            a0[mi] = *(const f16x8*)&Ab[(wr * 128 + mi * 16 + fr) * BK2 + rcol];
        if (st) {
            gload16(&As[pb][tid * 8],        gA0 + (t + 2) * BK2);
            gload16(&As[pb][4096 + tid * 8], gA1 + (t + 2) * BK2);
        }
        __builtin_amdgcn_s_setprio(1);
#pragma unroll
        for (int mi = 0; mi < 4; ++mi)
#pragma unroll
            for (int ni = 0; ni < 4; ++ni)
                acc[mi][ni] = __builtin_amdgcn_mfma_f32_16x16x32_f16(a0[mi], bbf[ni], acc[mi][ni], 0, 0, 0);
        __builtin_amdgcn_s_setprio(0);
        // (mid-tile barrier removed -- no hazard; see header comment)

        // ---- phase 1: A rows 64..127 of wave band; stage B of tile t+2 ----
        f16x8 a1[4];
#pragma unroll
        for (int mi = 0; mi < 4; ++mi)
            a1[mi] = *(const f16x8*)&Ab[(wr * 128 + 64 + mi * 16 + fr) * BK2 + rcol];
        if (st) {
            gload16(&Bs[pb][tid * 8],        gB0 + (t + 2) * BK2);
            gload16(&Bs[pb][4096 + tid * 8], gB1 + (t + 2) * BK2);
        }
        __builtin_amdgcn_s_setprio(1);
#pragma unroll
        for (int mi = 0; mi < 4; ++mi)
#pragma unroll
            for (int ni = 0; ni < 4; ++ni)
                acc[4 + mi][ni] = __builtin_amdgcn_mfma_f32_16x16x32_f16(a1[mi], bbf[ni], acc[4 + mi][ni], 0, 0, 0);
        __builtin_amdgcn_s_setprio(0);

        // ---- tile boundary: counted wait (never 0 until the pipeline drains) ----
        if (t < NT2 - 2) {
            asm volatile("s_waitcnt vmcnt(4)" ::: "memory");
        } else if (t == NT2 - 2) {
            asm volatile("s_waitcnt vmcnt(0)" ::: "memory");
        }
        if (t < NT2 - 1) {
            __builtin_amdgcn_s_barrier();
            asm volatile("" ::: "memory");
        }
    }

    // ---- epilogue: inline cbn (16 partials, fixed order) + float-domain best2.
    // Exact ties imply gap < TAU -> flagged -> rescue recomputes in fp32 with
    // u64 smallest-k tie-breaking, so reference argmin semantics are preserved.
    float cbv[4];
#pragma unroll
    for (int ni = 0; ni < 4; ++ni) {
        const int k = k0 + wc * 64 + ni * 16 + fr;
        float s = 0.f;
#pragma unroll
        for (int j = 0; j < 16; ++j) s += partial[(size_t)j * NK + k];
        cbv[ni] = s;
    }
    const int kt64 = (k0 >> 6) + wc;
#pragma unroll
    for (int mi = 0; mi < 8; ++mi) {
#pragma unroll
        for (int reg = 0; reg < 4; ++reg) {
            float b1f = 1e30f, b2f = 1e30f;
            int b1k = 0;
#pragma unroll
            for (int ni = 0; ni < 4; ++ni) {
                float s = fmaf(-2.f, acc[mi][ni][reg], cbv[ni]);
                b2f = fminf(fmaxf(s, b1f), b2f);   // med3: new 2nd-best
                if (s < b1f) { b1f = s; b1k = k0 + wc * 64 + ni * 16 + fr; }
            }
#pragma unroll
            for (int m = 8; m >= 1; m >>= 1) {
                float q1 = __shfl_xor(b1f, m);
                int   qk = __shfl_xor(b1k, m);
                float q2 = __shfl_xor(b2f, m);
                b2f = fminf(fminf(b2f, q2), fmaxf(b1f, q1));
                if (q1 < b1f) { b1f = q1; b1k = qk; }
            }
            if (fr == 0) {
                int n = n0 + wr * 128 + mi * 16 + fq * 4 + reg;
                ulonglong2 v;
                v.x = ((u64)fkey(b1f) << 32) | (unsigned)b1k;
                v.y = ((u64)fkey(b2f) << 32) | 0xffffffffu;
                tp[(size_t)kt64 * NK + n] = v;
            }
        }
    }
}

// ---------------- reduce 64 groups/token (4 stripes + LDS merge); flag near-ties ----------------
__global__ __launch_bounds__(256) void reduce_rows(
        const ulonglong2* __restrict__ tp, int* __restrict__ idx,
        int* __restrict__ rescue, int* __restrict__ ctr) {
    __shared__ ulonglong2 sh[4][64];
    const int no = threadIdx.x & 63, st = threadIdx.x >> 6;
    const int n = blockIdx.x * 64 + no;
    u64 b1 = ~0ull, b2 = ~0ull;
#pragma unroll 4
    for (int g = st * 16; g < st * 16 + 16; ++g) {
        ulonglong2 e = tp[(size_t)g * NK + n];
        u64 nb1 = umin64(b1, e.x);
        u64 nb2 = umin64(umax64(b1, e.x), umin64(b2, e.y));
        b1 = nb1; b2 = nb2;
    }
    ulonglong2 v; v.x = b1; v.y = b2;
    sh[st][no] = v;
    __syncthreads();
    if (st == 0) {
#pragma unroll
        for (int j = 1; j < 4; ++j) {
            ulonglong2 e = sh[j][no];
            u64 nb1 = umin64(b1, e.x);
            u64 nb2 = umin64(umax64(b1, e.x), umin64(b2, e.y));
            b1 = nb1; b2 = nb2;
        }
        idx[n] = (int)(b1 & 0xffffffffull);
        float f1 = unfkey((uint32_t)(b1 >> 32));
        float f2 = unfkey((uint32_t)(b2 >> 32));
        if (f2 - f1 < TAU) {
            int p = atomicAdd(ctr, 1);
            rescue[p] = n;
        }
    }
}

// ---------------- candidate-pruned exact fp32 rescore; writes idx directly ----------------
__global__ __launch_bounds__(256) void rescue_kernel(
        const float* __restrict__ z, const float* __restrict__ cb,
        const ulonglong2* __restrict__ tp, const int* __restrict__ rescue,
        const int* __restrict__ ctr, int* __restrict__ idx) {
    const int cnt = min(*ctr, NK);
    const int tid = threadIdx.x;
    const int lane = tid & 63, wv = tid >> 6;

    __shared__ float zn[D];
    __shared__ int cand[MAXC];
    __shared__ int ccnt, overflow;
    __shared__ u64 wred[4];

    for (int slot = blockIdx.x; slot < cnt; slot += gridDim.x) {
        const int n = rescue[slot];
        if (tid == 0) { ccnt = 0; overflow = 0; }
        for (int d = tid; d < D; d += 256) zn[d] = z[(size_t)d * NK + n];

        if (tid < 64) {   // wave 0: build candidate list
            ulonglong2 e = tp[(size_t)tid * NK + n];
            u64 m = e.x;
#pragma unroll
            for (int msk = 32; msk >= 1; msk >>= 1) m = umin64(m, __shfl_xor(m, msk));
            const float thr = unfkey((uint32_t)(m >> 32)) + CW;
            if (unfkey((uint32_t)(e.y >> 32)) < thr) {
                int p = atomicAdd(&ccnt, 64);
                if (p + 64 <= MAXC) {
                    for (int j = 0; j < 64; ++j) cand[p + j] = tid * 64 + j;
                } else overflow = 1;
            } else if (unfkey((uint32_t)(e.x >> 32)) < thr) {
                int p = atomicAdd(&ccnt, 1);
                if (p < MAXC) cand[p] = (int)(e.x & 0xffffffffull);
                else overflow = 1;
            }
        }
        __syncthreads();

        const int ovf = overflow;
        const int m = ovf ? NK : min(ccnt, MAXC);
        u64 best = ~0ull;
        for (int ci = wv; ci < m; ci += 4) {
            const int k = ovf ? ci : cand[ci];
            float s = 0.f, s2 = 0.f;
#pragma unroll
            for (int j = 0; j < 16; ++j) {
                float c = cb[(size_t)(lane + j * 64) * NK + k];
                s  = fmaf(zn[lane + j * 64], c, s);
                s2 = fmaf(c, c, s2);
            }
#pragma unroll
            for (int msk = 32; msk >= 1; msk >>= 1) {
                s  += __shfl_xor(s, msk);
                s2 += __shfl_xor(s2, msk);
            }
            float sc = s2 - 2.f * s;
            best = umin64(best, ((u64)fkey(sc) << 32) | (unsigned)k);
        }
        if (lane == 0) wred[wv] = best;
        __syncthreads();
        if (tid == 0)
            idx[n] = (int)(umin64(umin64(wred[0], wred[1]),
                                  umin64(wred[2], wred[3])) & 0xffffffffull);
        __syncthreads();   // protect zn/cand/ccnt reuse on the next strided slot
    }
}

// ---------------- fallback fp32 VALU GEMM (round-1, for small ws) ----------------
__global__ __launch_bounds__(256) void gemm_argmin(
        const float* __restrict__ z, const float* __restrict__ cb,
        const float* __restrict__ cbn, unsigned long long* __restrict__ best) {
    __shared__ float Zs[8][128];
    __shared__ float Cs[8][128];
    const int n0 = blockIdx.y * 128, k0 = blockIdx.x * 128;
    const int tid = threadIdx.x;
    const int tx = tid & 15, ty = tid >> 4;
    const int lr = tid >> 5, lc = (tid & 31) << 2;
    float acc[8][8];
#pragma unroll
    for (int i = 0; i < 8; ++i)
#pragma unroll
        for (int j = 0; j < 8; ++j) acc[i][j] = 0.f;
    for (int d0 = 0; d0 < D; d0 += 8) {
        float4 zv = *(const float4*)&z [(d0 + lr) * NK + n0 + lc];
        float4 cv = *(const float4*)&cb[(d0 + lr) * NK + k0 + lc];
        __syncthreads();
        *(float4*)&Zs[lr][lc] = zv;
        *(float4*)&Cs[lr][lc] = cv;
        __syncthreads();
#pragma unroll
        for (int dd = 0; dd < 8; ++dd) {
            float4 a0 = *(const float4*)&Zs[dd][ty * 8];
            float4 a1 = *(const float4*)&Zs[dd][ty * 8 + 4];
            float4 b0 = *(const float4*)&Cs[dd][tx * 8];
            float4 b1 = *(const float4*)&Cs[dd][tx * 8 + 4];
            float a[8] = {a0.x, a0.y, a0.z, a0.w, a1.x, a1.y, a1.z, a1.w};
            float b[8] = {b0.x, b0.y, b0.z, b0.w, b1.x, b1.y, b1.z, b1.w};
#pragma unroll
            for (int i = 0; i < 8; ++i)
#pragma unroll
                for (int j = 0; j < 8; ++j) acc[i][j] = fmaf(a[i], b[j], acc[i][j]);
        }
    }
    float cbnv[8];
#pragma unroll
    for (int j = 0; j < 8; ++j) cbnv[j] = cbn[k0 + tx * 8 + j];
#pragma unroll
    for (int i = 0; i < 8; ++i) {
        float bv = cbnv[0] - 2.f * acc[i][0];
        int bj = 0;
#pragma unroll
        for (int j = 1; j < 8; ++j) {
            float v = cbnv[j] - 2.f * acc[i][j];
            if (v < bv) { bv = v; bj = j; }
        }
        u64 p = ((u64)fkey(bv) << 32) | (unsigned)(k0 + tx * 8 + bj);
#pragma unroll
        for (int m = 8; m >= 1; m >>= 1) {
            u64 q = __shfl_xor(p, m);
            if (q < p) p = q;
        }
        if (tx == 0) atomicMin(&best[n0 + ty * 8 + i], p);
    }
}

__global__ void extract_idx(const unsigned long long* __restrict__ best,
                            int* __restrict__ idx) {
    int n = blockIdx.x * 256 + threadIdx.x;
    idx[n] = (int)(unsigned)(best[n] & 0xFFFFFFFFull);
}

// ---------------- gather + straight-through (float4) ----------------
__global__ void gather_kernel(const float* __restrict__ z, const float* __restrict__ cb,
                              const int* __restrict__ idx, float* __restrict__ out) {
    const int d = blockIdx.x;
    const float* cbrow = &cb[(size_t)d * NK];
    const float* zrow  = &z [(size_t)d * NK];
    float* st = &out[(size_t)d * NK];
    float* zq = &out[(size_t)D * NK + (size_t)d * NK];
    for (int n4 = threadIdx.x; n4 < NK / 4; n4 += 256) {
        int4 iv = *(const int4*)&idx[n4 * 4];
        float4 zv = *(const float4*)&zrow[n4 * 4];
        float4 q;
        q.x = cbrow[iv.x]; q.y = cbrow[iv.y]; q.z = cbrow[iv.z]; q.w = cbrow[iv.w];
        float4 stv;
        stv.x = q.x + (zv.x - q.x);
        stv.y = q.y + (zv.y - q.y);
        stv.z = q.z + (zv.z - q.z);
        stv.w = q.w + (zv.w - q.w);
        *(float4*)&st[n4 * 4] = stv;
        *(float4*)&zq[n4 * 4] = q;
    }
}

extern "C" void kernel_launch(void* const* d_in, const int* in_sizes, int n_in,
                              void* d_out, int out_size, void* d_ws, size_t ws_size,
                              hipStream_t stream) {
    const float* z  = (const float*)d_in[0];
    const float* cb = (const float*)d_in[1];
    float* out = (float*)d_out;
    char* ws = (char*)d_ws;

    const size_t oA  = 0;
    const size_t oB  = oA + (size_t)NK * KA * 2;
    const size_t oT  = oB + (size_t)NK * KB * 2;
    const size_t oI  = oT + (size_t)NK * 64 * 16;
    const size_t oR  = oI + NK * 4;
    const size_t oN  = oR + NK * 4;
    const size_t oP  = oN + 256;
    const size_t REQ = oP + (size_t)16 * NK * 4;

    if (ws_size >= REQ) {
        _Float16* Ap = (_Float16*)(ws + oA);
        _Float16* Bp = (_Float16*)(ws + oB);
        ulonglong2* tp = (ulonglong2*)(ws + oT);
        int* idx = (int*)(ws + oI);
        int* rescue = (int*)(ws + oR);
        int* ctr = (int*)(ws + oN);
        float* partial = (float*)(ws + oP);

        split_transpose<<<dim3(NK / 64, D / 64, 2), 256, 0, stream>>>(z, cb, Ap, Bp, partial, ctr);
        gemm_mfma<<<256, 512, 0, stream>>>(Ap, Bp, partial, tp);
        reduce_rows<<<64, 256, 0, stream>>>(tp, idx, rescue, ctr);
        rescue_kernel<<<256, 256, 0, stream>>>(z, cb, tp, rescue, ctr, idx);
        gather_kernel<<<1024, 256, 0, stream>>>(z, cb, idx, out);
    } else {
        unsigned long long* best = (unsigned long long*)ws;
        float* cbn = (float*)(ws + NK * 8);
        int* idx = (int*)(ws + NK * 8 + NK * 4);
        hipMemsetAsync(best, 0xFF, NK * 8, stream);
        cbnorm_kernel<<<64, 256, 0, stream>>>(cb, cbn);
        gemm_argmin<<<dim3(NK / 128, NK / 128), 256, 0, stream>>>(z, cb, cbn, best);
        extract_idx<<<16, 256, 0, stream>>>(best, idx);
        gather_kernel<<<1024, 256, 0, stream>>>(z, cb, idx, out);
    }
}